// Round 13
// baseline (677.183 us; speedup 1.0000x reference)
//
#include <hip/hip_runtime.h>
#include <hip/hip_cooperative_groups.h>

namespace cg = cooperative_groups;

// CapsNet dynamic routing — fp32 in / fp32 out (verified R11/R12).
// Single cooperative kernel: 3 routing passes + 3 squash steps fused with
// grid.sync(). 768 blocks = 3/CU co-resident. Fallback: R12's 6-dispatch path.
// B=64, Ni=1152, Di=8, No=64, Do=16.
// u[b,i,o,d] = sum_k W[i*8192 + (o*16+d)*8 + k] * x[b*9216 + i*8 + k]
// it0: c=1/64       -> s0 -> v0
// it1: l=<u,v0>     -> c1 -> s1 -> v1
// it2: l=<u,v0+v1>  -> c2 (OUT [B,Ni,No]) -> s2 -> v2 (OUT [B,No,Do])

#define B_      64
#define NI_     1152
#define DI_     8
#define NO_     64
#define DO_     16
#define NOD_    1024
#define CH_     96
#define CI_     12
#define BG_     8
#define BSPLIT_ 8
#define V_ELEMS 65536

static_assert(CH_ * CI_ == NI_, "chunking");

__global__ __launch_bounds__(256, 3)
void caps_fused(const float* __restrict__ X, const float* __restrict__ W,
                float* __restrict__ part, float* __restrict__ v0ws,
                float* __restrict__ w01ws,
                float* __restrict__ outv, float* __restrict__ outc)
{
    __shared__ float x_lds[BG_][CI_ * DI_];   // 3 KB
    __shared__ float v_lds[BG_][NOD_];        // 32 KB
    __shared__ float e_lds[BG_][NO_];         // 2 KB
    __shared__ float invS[BG_];

    cg::grid_group grid = cg::this_grid();

    const int t   = threadIdx.x;
    const int lin = blockIdx.x;          // 0..767
    const int ch  = lin % CH_;           // same-ch blocks 96 apart -> same XCD (heuristic)
    const int b0  = (lin / CH_) * BG_;
    const int i0  = ch * CI_;
    const int o   = t >> 2;

    // stage x once for all 3 phases
    for (int f = t; f < BG_ * CI_ * DI_ / 4; f += 256) {
        int b = f / (CI_ * DI_ / 4), r = f - b * (CI_ * DI_ / 4);
        ((float4*)x_lds)[f] =
            ((const float4*)(X + ((size_t)(b0 + b) * NI_ + i0) * DI_))[r];
    }
    __syncthreads();

    const float4* Wq = (const float4*)W;

    for (int phase = 0; phase < 3; ++phase) {
        if (phase >= 1) {   // stage v (v0 or v0+v1) for this phase
            const float* vin = (phase == 1) ? v0ws : w01ws;
            const float4* vg = (const float4*)(vin + (size_t)b0 * NOD_);
            float4* vl = (float4*)(&v_lds[0][0]);
            for (int f = t; f < BG_ * NOD_ / 4; f += 256) vl[f] = vg[f];
            __syncthreads();
        }

        float acc[BG_][4];
#pragma unroll
        for (int b = 0; b < BG_; ++b) { acc[b][0]=0.f; acc[b][1]=0.f; acc[b][2]=0.f; acc[b][3]=0.f; }

        for (int ci = 0; ci < CI_; ++ci) {
            const int i = i0 + ci;
            float wf[4][8];   // W[i][o][4q+j][k], q=t&3: 32 contiguous floats at t*32
            {
                const size_t base = (size_t)i * 2048 + (size_t)t * 8;
#pragma unroll
                for (int j = 0; j < 4; ++j) {
                    float4 q0 = Wq[base + 2*j], q1 = Wq[base + 2*j + 1];
                    wf[j][0]=q0.x; wf[j][1]=q0.y; wf[j][2]=q0.z; wf[j][3]=q0.w;
                    wf[j][4]=q1.x; wf[j][5]=q1.y; wf[j][6]=q1.z; wf[j][7]=q1.w;
                }
            }
            float u[BG_][4];
#pragma unroll
            for (int b = 0; b < BG_; ++b) {
                const float* xb = &x_lds[b][ci * DI_];
#pragma unroll
                for (int j = 0; j < 4; ++j) {
                    float s = 0.f;
#pragma unroll
                    for (int k = 0; k < 8; ++k) s = fmaf(wf[j][k], xb[k], s);
                    u[b][j] = s;
                }
                if (phase >= 1) {
                    const float* vb = &v_lds[b][4 * t];
                    float a = u[b][0]*vb[0] + u[b][1]*vb[1] + u[b][2]*vb[2] + u[b][3]*vb[3];
                    a += __shfl_xor(a, 1);
                    a += __shfl_xor(a, 2);         // full 16-d dot within quad
                    float e = __expf(a);
                    if ((t & 3) == 0) e_lds[b][o] = e;
                } else {
                    acc[b][0]+=u[b][0]; acc[b][1]+=u[b][1]; acc[b][2]+=u[b][2]; acc[b][3]+=u[b][3];
                }
            }
            if (phase >= 1) {
                __syncthreads();
                {
                    int bb = t >> 5, l = t & 31;
                    float s = e_lds[bb][l] + e_lds[bb][l + 32];
                    s += __shfl_xor(s, 1);  s += __shfl_xor(s, 2);  s += __shfl_xor(s, 4);
                    s += __shfl_xor(s, 8);  s += __shfl_xor(s, 16);
                    if (l == 0) invS[bb] = 1.0f / s;
                }
                __syncthreads();
#pragma unroll
                for (int b = 0; b < BG_; ++b) {
                    float c = e_lds[b][o] * invS[b];
                    acc[b][0] = fmaf(c, u[b][0], acc[b][0]);
                    acc[b][1] = fmaf(c, u[b][1], acc[b][1]);
                    acc[b][2] = fmaf(c, u[b][2], acc[b][2]);
                    acc[b][3] = fmaf(c, u[b][3], acc[b][3]);
                    if (phase == 2 && (t & 3) == 0)
                        outc[((size_t)(b0 + b) * NI_ + i) * NO_ + o] = c;
                }
                __syncthreads();
            }
        }

#pragma unroll
        for (int b = 0; b < BG_; ++b) {
            float4 val; val.x=acc[b][0]; val.y=acc[b][1]; val.z=acc[b][2]; val.w=acc[b][3];
            *((float4*)(part + (((size_t)(b0 + b) * CH_ + ch) * NOD_ + 4 * t))) = val;
        }
        grid.sync();

        // squash: blocks 0..255, one col per thread
        if (lin < 256) {
            const int col = lin * 256 + t;           // b*1024 + o*16 + d
            const int b = col >> 10, od = col & 1023;
            const float* p = part + (size_t)b * CH_ * NOD_ + od;
            float s = 0.f;
            for (int c2 = 0; c2 < CH_; ++c2) s += p[(size_t)c2 * NOD_];
            if (phase == 0) s *= (1.0f / 64.0f);
            float s2 = s * s;
            s2 += __shfl_xor(s2, 1); s2 += __shfl_xor(s2, 2);
            s2 += __shfl_xor(s2, 4); s2 += __shfl_xor(s2, 8);
            const float scale = s2 / ((1.0f + s2) * sqrtf(s2 + 1e-7f));
            const float v = scale * s;
            if (phase == 0)      v0ws[col]  = v;
            else if (phase == 1) w01ws[col] = v0ws[col] + v;
            else                 outv[col]  = v;
        }
        if (phase < 2) grid.sync();
    }
}

// ---- R12 fallback path (proven passing) ----
template <int MODE>
__global__ __launch_bounds__(256, 3)
void caps_pass(const float* __restrict__ X, const float* __restrict__ W,
               const float* __restrict__ vin, float* __restrict__ part,
               float* __restrict__ rw)
{
    __shared__ float x_lds[BG_][CI_ * DI_];
    __shared__ float v_lds[BG_][NOD_];
    __shared__ float e_lds[BG_][NO_];
    __shared__ float invS[BG_];

    const int t  = threadIdx.x;
    const int ch = blockIdx.x;
    const int b0 = blockIdx.y * BG_;
    const int i0 = ch * CI_;
    const int o  = t >> 2;

    for (int f = t; f < BG_ * CI_ * DI_ / 4; f += 256) {
        int b = f / (CI_ * DI_ / 4), r = f - b * (CI_ * DI_ / 4);
        ((float4*)x_lds)[f] =
            ((const float4*)(X + ((size_t)(b0 + b) * NI_ + i0) * DI_))[r];
    }
    if (MODE >= 1) {
        const float4* vg = (const float4*)(vin + (size_t)b0 * NOD_);
        float4* vl = (float4*)(&v_lds[0][0]);
        for (int f = t; f < BG_ * NOD_ / 4; f += 256) vl[f] = vg[f];
    }
    __syncthreads();

    float acc[BG_][4];
#pragma unroll
    for (int b = 0; b < BG_; ++b) { acc[b][0]=0.f; acc[b][1]=0.f; acc[b][2]=0.f; acc[b][3]=0.f; }

    const float4* Wq = (const float4*)W;

    for (int ci = 0; ci < CI_; ++ci) {
        const int i = i0 + ci;
        float wf[4][8];
        {
            const size_t base = (size_t)i * 2048 + (size_t)t * 8;
#pragma unroll
            for (int j = 0; j < 4; ++j) {
                float4 q0 = Wq[base + 2*j], q1 = Wq[base + 2*j + 1];
                wf[j][0]=q0.x; wf[j][1]=q0.y; wf[j][2]=q0.z; wf[j][3]=q0.w;
                wf[j][4]=q1.x; wf[j][5]=q1.y; wf[j][6]=q1.z; wf[j][7]=q1.w;
            }
        }
        float u[BG_][4];
#pragma unroll
        for (int b = 0; b < BG_; ++b) {
            const float* xb = &x_lds[b][ci * DI_];
#pragma unroll
            for (int j = 0; j < 4; ++j) {
                float s = 0.f;
#pragma unroll
                for (int k = 0; k < 8; ++k) s = fmaf(wf[j][k], xb[k], s);
                u[b][j] = s;
            }
            if (MODE >= 1) {
                const float* vb = &v_lds[b][4 * t];
                float a = u[b][0]*vb[0] + u[b][1]*vb[1] + u[b][2]*vb[2] + u[b][3]*vb[3];
                a += __shfl_xor(a, 1);
                a += __shfl_xor(a, 2);
                float e = __expf(a);
                if ((t & 3) == 0) e_lds[b][o] = e;
            } else {
                acc[b][0]+=u[b][0]; acc[b][1]+=u[b][1]; acc[b][2]+=u[b][2]; acc[b][3]+=u[b][3];
            }
        }
        if (MODE >= 1) {
            __syncthreads();
            {
                int bb = t >> 5, l = t & 31;
                float s = e_lds[bb][l] + e_lds[bb][l + 32];
                s += __shfl_xor(s, 1);  s += __shfl_xor(s, 2);  s += __shfl_xor(s, 4);
                s += __shfl_xor(s, 8);  s += __shfl_xor(s, 16);
                if (l == 0) invS[bb] = 1.0f / s;
            }
            __syncthreads();
#pragma unroll
            for (int b = 0; b < BG_; ++b) {
                float c = e_lds[b][o] * invS[b];
                acc[b][0] = fmaf(c, u[b][0], acc[b][0]);
                acc[b][1] = fmaf(c, u[b][1], acc[b][1]);
                acc[b][2] = fmaf(c, u[b][2], acc[b][2]);
                acc[b][3] = fmaf(c, u[b][3], acc[b][3]);
                if (MODE == 2 && (t & 3) == 0)
                    rw[((size_t)(b0 + b) * NI_ + i) * NO_ + o] = c;
            }
            __syncthreads();
        }
    }

#pragma unroll
    for (int b = 0; b < BG_; ++b) {
        float4 val; val.x=acc[b][0]; val.y=acc[b][1]; val.z=acc[b][2]; val.w=acc[b][3];
        *((float4*)(part + (((size_t)(b0 + b) * CH_ + ch) * NOD_ + 4 * t))) = val;
    }
}

template <int MODE>
__global__ __launch_bounds__(256)
void caps_squash(const float* __restrict__ part, const float* __restrict__ v0in,
                 float* __restrict__ vout, int nch)
{
    const int col = blockIdx.x * 256 + threadIdx.x;
    const int b = col >> 10, od = col & 1023;
    const float* p = part + (size_t)b * nch * NOD_ + od;
    float s = 0.f;
    for (int ch = 0; ch < nch; ++ch) s += p[(size_t)ch * NOD_];
    if (MODE == 0) s *= (1.0f / 64.0f);
    float s2 = s * s;
    s2 += __shfl_xor(s2, 1); s2 += __shfl_xor(s2, 2);
    s2 += __shfl_xor(s2, 4); s2 += __shfl_xor(s2, 8);
    const float scale = s2 / ((1.0f + s2) * sqrtf(s2 + 1e-7f));
    const float v = scale * s;
    if (MODE == 1) vout[col] = v0in[col] + v;
    else           vout[col] = v;
}

extern "C" void kernel_launch(void* const* d_in, const int* in_sizes, int n_in,
                              void* d_out, int out_size, void* d_ws, size_t ws_size,
                              hipStream_t stream)
{
    const float *X, *W;
    if (in_sizes[0] < in_sizes[1]) { X = (const float*)d_in[0]; W = (const float*)d_in[1]; }
    else                           { X = (const float*)d_in[1]; W = (const float*)d_in[0]; }

    float* out  = (float*)d_out;
    float* outv = out;             // v: [B,No,Do] fp32
    float* outc = out + V_ELEMS;   // c: [B,Ni,No] fp32

    float* part = (float*)d_ws;                      // 25.2 MB (ws >= 64 MB measured R12)
    float* v0   = part + (size_t)B_ * CH_ * NOD_;
    float* w01  = v0 + (size_t)B_ * NOD_;

    // Try the fused cooperative kernel; fall back to the proven 6-dispatch path.
    void* args[] = { (void*)&X, (void*)&W, (void*)&part, (void*)&v0,
                     (void*)&w01, (void*)&outv, (void*)&outc };
    hipError_t err = hipLaunchCooperativeKernel((const void*)caps_fused,
                                                dim3(CH_ * BSPLIT_), dim3(256),
                                                args, 0, stream);
    if (err == hipSuccess) return;
    (void)hipGetLastError();   // clear sticky error; fall through to fallback

    dim3 gP(CH_, BSPLIT_), blk(256);
    caps_pass<0><<<gP, blk, 0, stream>>>(X, W, nullptr, part, nullptr);
    caps_squash<0><<<256, blk, 0, stream>>>(part, nullptr, v0, CH_);
    caps_pass<1><<<gP, blk, 0, stream>>>(X, W, v0, part, nullptr);
    caps_squash<1><<<256, blk, 0, stream>>>(part, v0, w01, CH_);
    caps_pass<2><<<gP, blk, 0, stream>>>(X, W, w01, part, outc);
    caps_squash<2><<<256, blk, 0, stream>>>(part, nullptr, outv, CH_);
}